// Round 4
// baseline (157.693 us; speedup 1.0000x reference)
//
#include <hip/hip_runtime.h>
#include <hip/hip_bf16.h>

// TriplesDistances: B=16, N=512, A=1024
// positions: float32 [B,N,3]; neighbors_j/k: int32 [B,N,A]; out: FLOAT32,
// (r_ij | r_ik | r_jk) each [B,N,A] concatenated flat.
//
// Dtype triangulation (R0-R2): bf16-pos read gave NaN (=> pos f32); int64-idx
// read faulted (=> idx int32); bf16 out write gave finite-garbage absmax ~= ref
// max (=> out f32).
//
// Memory-bound: 67 MB idx reads + 100 MB f32 writes => ~27 us floor @6.3 TB/s.
// One block per (b,n) row; batch-b positions staged to LDS as f32 (random
// stride-3 gathers average ~2 lanes/bank, free on gfx950 per m136).

namespace {
constexpr int kB = 16;
constexpr int kN = 512;
constexpr int kA = 1024;
constexpr long long kBNA = (long long)kB * kN * kA;  // 8,388,608
}  // namespace

__global__ __launch_bounds__(256) void TriplesDistances_kernel(
    const float* __restrict__ pos,   // f32 [B*N*3]
    const int* __restrict__ nj,      // int32 [B*N*A]
    const int* __restrict__ nk,      // int32 [B*N*A]
    float* __restrict__ out)         // f32 [3*B*N*A]
{
    __shared__ float spos[kN * 3];  // 6 KB, f32 positions of this block's batch

    const int bn  = blockIdx.x;        // (b,n) flattened, 0..B*N
    const int b   = bn >> 9;           // / N
    const int n   = bn & (kN - 1);     // % N
    const int tid = threadIdx.x;

    // Stage batch-b positions: 1536 floats; 6 per thread, coalesced dwords.
    {
        const float* p = pos + (size_t)b * (kN * 3);
#pragma unroll
        for (int t = 0; t < 6; ++t) {
            const int e = tid + t * 256;
            spos[e] = p[e];
        }
    }
    __syncthreads();

    const float xi = spos[n * 3 + 0];
    const float yi = spos[n * 3 + 1];
    const float zi = spos[n * 3 + 2];

    const long long rowbase = (long long)bn * kA + tid * 4;  // element index
    const int4 j4 = *(const int4*)(nj + rowbase);  // 16B coalesced
    const int4 k4 = *(const int4*)(nk + rowbase);

    const int js[4] = {j4.x, j4.y, j4.z, j4.w};
    const int ks[4] = {k4.x, k4.y, k4.z, k4.w};

    float rij[4], rik[4], rjk[4];
#pragma unroll
    for (int t = 0; t < 4; ++t) {
        const int j3 = js[t] * 3;
        const int k3 = ks[t] * 3;
        const float xj = spos[j3 + 0], yj = spos[j3 + 1], zj = spos[j3 + 2];
        const float xk = spos[k3 + 0], yk = spos[k3 + 1], zk = spos[k3 + 2];

        // safe_norm: sqrtf(0)=0 matches where(s>0, sqrt(s), 0)
        float dx = xj - xi, dy = yj - yi, dz = zj - zi;
        rij[t] = sqrtf(dx * dx + dy * dy + dz * dz);

        dx = xk - xi; dy = yk - yi; dz = zk - zi;
        rik[t] = sqrtf(dx * dx + dy * dy + dz * dz);

        dx = xj - xk; dy = yj - yk; dz = zj - zk;
        rjk[t] = sqrtf(dx * dx + dy * dy + dz * dz);
    }

    // 16B coalesced f32 stores to each of the three output planes.
    *(float4*)(out + rowbase) =
        make_float4(rij[0], rij[1], rij[2], rij[3]);
    *(float4*)(out + kBNA + rowbase) =
        make_float4(rik[0], rik[1], rik[2], rik[3]);
    *(float4*)(out + 2 * kBNA + rowbase) =
        make_float4(rjk[0], rjk[1], rjk[2], rjk[3]);
}

extern "C" void kernel_launch(void* const* d_in, const int* in_sizes, int n_in,
                              void* d_out, int out_size, void* d_ws, size_t ws_size,
                              hipStream_t stream) {
    const float* pos = (const float*)d_in[0];
    const int* nj = (const int*)d_in[1];
    const int* nk = (const int*)d_in[2];
    float* out = (float*)d_out;

    TriplesDistances_kernel<<<kB * kN, 256, 0, stream>>>(pos, nj, nk, out);
}